// Round 2
// baseline (79.813 us; speedup 1.0000x reference)
//
#include <hip/hip_runtime.h>
#include <hip/hip_bf16.h>

typedef __attribute__((ext_vector_type(8))) short short8;
typedef __attribute__((ext_vector_type(4))) float f32x4;
typedef __attribute__((ext_vector_type(16))) float f32x16;

#define B_  32
#define CH  256
#define S_  1024
#define NH  8
#define HD  32

static __device__ __forceinline__ unsigned short f2bf(float f) {
  __hip_bfloat16 h = __float2bfloat16(f);
  return *reinterpret_cast<unsigned short*>(&h);
}

// Async global->LDS DMA, 16B per lane. LDS dest = wave-uniform base + lane*16.
static __device__ __forceinline__ void gl_lds16(const void* g, void* l) {
  __builtin_amdgcn_global_load_lds(
      (const __attribute__((address_space(1))) void*)g,
      (__attribute__((address_space(3))) void*)l, 16, 0, 0);
}

// ---------------- Kernel 1: prep = xpose (blocks 0..8191) + wconv (8192..) ---
// xpose: x (B,C,S) fp32 -> xt (B,S,C) bf16 via 32x32 LDS tile.
// wconv: fold (1/sqrt(32))*log2(e) into Q weights+bias, convert to bf16;
// scores then live in the log2 domain -> softmax exp is a bare v_exp_f32.
__global__ void k_prep(const float* __restrict__ x, unsigned short* __restrict__ xt,
                       const float* __restrict__ qw, const float* __restrict__ qb,
                       const float* __restrict__ kvw, const float* __restrict__ kvb,
                       unsigned short* __restrict__ wt, float* __restrict__ bias) {
  __shared__ float tile[32][33];
  int blk = (int)blockIdx.x;
  int t = threadIdx.x;
  if (blk < 8192) {                                   // ---- xpose ----
    int b = blk >> 8;
    int inner = blk & 255;
    int ct = inner >> 5, st = inner & 31;             // 8 c-tiles x 32 s-tiles
    int c0 = ct * 32, s0 = st * 32;
    int r = t >> 3, q4 = (t & 7) * 4;
    const float4 v = *reinterpret_cast<const float4*>(
        x + ((size_t)(b * CH + c0 + r)) * S_ + s0 + q4);
    tile[r][q4 + 0] = v.x; tile[r][q4 + 1] = v.y;
    tile[r][q4 + 2] = v.z; tile[r][q4 + 3] = v.w;
    __syncthreads();
    ushort4 u;
    u.x = f2bf(tile[q4 + 0][r]); u.y = f2bf(tile[q4 + 1][r]);
    u.z = f2bf(tile[q4 + 2][r]); u.w = f2bf(tile[q4 + 3][r]);
    *reinterpret_cast<ushort4*>(xt + ((size_t)(b * S_ + s0 + r)) * CH + c0 + q4) = u;
  } else {                                            // ---- wconv ----
    int gid = (blk - 8192) * 256 + t;                 // 0..196607
    const float rs = 0.25503531838951954f;            // log2(e)/sqrt(32)
    int o = gid >> 8, c = gid & 255;
    float v = (o < 256) ? qw[o * 256 + c] * rs : kvw[(o - 256) * 256 + c];
    wt[gid] = f2bf(v);
    if (gid < 768) bias[gid] = (gid < 256) ? qb[gid] * rs : kvb[gid - 256];
  }
}

// ---------------- Kernel 2: projection GEMM (768x1024x256 per batch) ---------
// R19 (= R18 with the compute-buffer typo fixed: PROJ_COMPUTE takes step%3,
// not step). Triple-buffered, depth-2 prefetch, raw s_barrier + counted
// vmcnt(4) (T3/T4: loads stay in flight across barriers; never drain to 0 in
// the loop). LDS per buffer is kb-PLANE-MAJOR [kb][row][8]: each quarter-wave
// ds_read_b128 reads 16x16B contiguous -> bank-conflict-free (old [row][kb*8]
// layout strided 64B -> 1.57M conflict cycles). DMA dest stays linear
// (wave-uniform base + lane*16); only per-lane GLOBAL sources change.
//
// Schedule (fully unrolled, 8 K-steps of 32):
//   prologue: issue step0->b0, step1->b1
//   step k:   vmcnt(4)  [own step-k DMAs landed; step-k+1's 4 in flight]
//             s_barrier [all waves' step-k DMAs landed]
//             issue step k+2 -> buf (k+2)%3  [WAR-safe: buf last read at step
//                                             k-1, all waves past this barrier]
//             16 MFMA from buf k%3
// K and V written in the PLANE-MAJOR PER-TILE layout k_attn stages:
//   kv[bh][t][0..1023]   : K-tile - plane p (dims 8p..8p+7) x 32 keys x 8
//   kv[bh][t][1024..2047]: V-tile - plane s (sigma-keys 8s..8s+7) x 32 dims x 8
// sigma = swap bits 2<->3 of the local key index (PV B-fragment order).

#define VMW(n) asm volatile("s_waitcnt vmcnt(" #n ")" ::: "memory")
#define BARX() asm volatile("s_barrier" ::: "memory")

#define PROJ_ISSUE(step, buf) do {                                  \
    gl_lds16(wa + (step) * 32,      asb + (buf) * 8192 + wb);       \
    gl_lds16(wa + (step) * 32 + 16, asb + (buf) * 8192 + 4096 + wb);\
    gl_lds16(xa + (step) * 32,      bsb + (buf) * 8192 + wb);       \
    gl_lds16(xa + (step) * 32 + 16, bsb + (buf) * 8192 + 4096 + wb);\
  } while (0)

#define PROJ_COMPUTE(buf) do {                                      \
    short8 af[4], bfv[4];                                           \
    _Pragma("unroll")                                               \
    for (int mf = 0; mf < 4; ++mf)                                  \
      af[mf] = *reinterpret_cast<const short8*>(                    \
          &As[buf][rb * 1024 + (wm + mf * 16 + lr) * 8]);           \
    _Pragma("unroll")                                               \
    for (int nf = 0; nf < 4; ++nf)                                  \
      bfv[nf] = *reinterpret_cast<const short8*>(                   \
          &Bs[buf][rb * 1024 + (wn + nf * 16 + lr) * 8]);           \
    _Pragma("unroll")                                               \
    for (int mf = 0; mf < 4; ++mf)                                  \
      _Pragma("unroll")                                             \
      for (int nf = 0; nf < 4; ++nf)                                \
        acc[mf][nf] = __builtin_amdgcn_mfma_f32_16x16x32_bf16(      \
            af[mf], bfv[nf], acc[mf][nf], 0, 0, 0);                 \
  } while (0)

__global__ __launch_bounds__(256) void k_proj(
    const unsigned short* __restrict__ wt, const float* __restrict__ bias,
    const unsigned short* __restrict__ xt,
    unsigned short* __restrict__ qws, unsigned short* __restrict__ kv) {
  __shared__ __align__(16) unsigned short As[3][4096];  // [buf][kb*1024+row*8]
  __shared__ __align__(16) unsigned short Bs[3][4096];  // 48KB total
  int b = blockIdx.y;
  int mt = blockIdx.x >> 3, nt = blockIdx.x & 7;      // 6 m-tiles x 8 n-tiles
  int tid = threadIdx.x;
  int wid = tid >> 6, l = tid & 63;
  int rb = l >> 4, lr = l & 15;
  int wr = wid >> 1, wc = wid & 1;
  int mb = mt * 128, nb = nt * 128;                   // block tile bases
  int wm = wr * 64, wn = wc * 64;                     // wave offsets in tile
  const unsigned short* xb = xt + (size_t)b * S_ * CH;

  // Per-lane global sources for kb-plane-major LDS:
  // thread t lands at LDS short-offset t*8 = kb2*1024 + rrow*8
  // (first gl_lds16: kb = kb2 in {0,1}; second (+4096B): kb = kb2+2).
  int rrow = tid & 127, kb2 = tid >> 7;
  const unsigned short* wa = wt + (size_t)(mb + rrow) * CH + kb2 * 8;
  const unsigned short* xa = xb + (size_t)(nb + rrow) * CH + kb2 * 8;
  char* asb = (char*)&As[0][0];
  char* bsb = (char*)&Bs[0][0];
  int wb = wid * 1024;                                // wave-uniform DMA base

  f32x4 acc[4][4];
  #pragma unroll
  for (int mf = 0; mf < 4; ++mf)
    #pragma unroll
    for (int nf = 0; nf < 4; ++nf)
      acc[mf][nf] = (f32x4){0.f, 0.f, 0.f, 0.f};

  PROJ_ISSUE(0, 0); PROJ_ISSUE(1, 1);                 // prologue: 8 DMAs

  VMW(4); BARX(); PROJ_ISSUE(2, 2); PROJ_COMPUTE(0);  // step 0
  VMW(4); BARX(); PROJ_ISSUE(3, 0); PROJ_COMPUTE(1);  // step 1
  VMW(4); BARX(); PROJ_ISSUE(4, 1); PROJ_COMPUTE(2);  // step 2
  VMW(4); BARX(); PROJ_ISSUE(5, 2); PROJ_COMPUTE(0);  // step 3
  VMW(4); BARX(); PROJ_ISSUE(6, 0); PROJ_COMPUTE(1);  // step 4
  VMW(4); BARX(); PROJ_ISSUE(7, 1); PROJ_COMPUTE(2);  // step 5
  VMW(4); BARX();                   PROJ_COMPUTE(0);  // step 6
  VMW(0); BARX();                   PROJ_COMPUTE(1);  // step 7

  #pragma unroll
  for (int mf = 0; mf < 4; ++mf) {
    int m0 = mb + wm + mf * 16 + rb * 4;
    const float4 bv = *reinterpret_cast<const float4*>(bias + m0);
    #pragma unroll
    for (int nf = 0; nf < 4; ++nf) {
      int n = nb + wn + nf * 16 + lr;                 // spatial s (key index)
      float v0 = acc[mf][nf][0] + bv.x;
      float v1 = acc[mf][nf][1] + bv.y;
      float v2 = acc[mf][nf][2] + bv.z;
      float v3 = acc[mf][nf][3] + bv.w;
      if (m0 < 256) {
        int h = m0 >> 5, d = m0 & 31;
        ushort4 u = {f2bf(v0), f2bf(v1), f2bf(v2), f2bf(v3)};
        *reinterpret_cast<ushort4*>(
            qws + ((size_t)(b * NH + h) * S_ + n) * HD + d) = u;
      } else if (m0 < 512) {
        int mm = m0 - 256; int h = mm >> 5, d0 = mm & 31;   // dims d0..d0+3
        size_t off = (((size_t)(b * NH + h) * 32 + (n >> 5)) * 2048)
                   + (size_t)((d0 >> 3) * 256 + (n & 31) * 8 + (d0 & 7));
        ushort4 u = {f2bf(v0), f2bf(v1), f2bf(v2), f2bf(v3)};
        *reinterpret_cast<ushort4*>(kv + off) = u;          // same plane: 8B store
      } else {
        int mm = m0 - 512; int h = mm >> 5, d0 = mm & 31;   // dims d0..d0+3
        int nl = n & 31;                                    // sigma: swap bits 2,3
        int kp = (nl & 19) | (((nl >> 2) & 1) << 3) | (((nl >> 3) & 1) << 2);
        size_t base = (((size_t)(b * NH + h) * 32 + (n >> 5)) * 2048) + 1024
                    + (size_t)((kp >> 3) * 256 + (kp & 7));
        kv[base + (size_t)(d0 + 0) * 8] = f2bf(v0);
        kv[base + (size_t)(d0 + 1) * 8] = f2bf(v1);
        kv[base + (size_t)(d0 + 2) * 8] = f2bf(v2);
        kv[base + (size_t)(d0 + 3) * 8] = f2bf(v3);
      }
    }
  }
}

// ---------------- Kernel 3: flash attention, strict causal -------------------
// R17 structure extended pair->QUAD per barrier: each iteration stages FOUR
// K/V tiles (16KB, two gl_lds16 calls per thread) double-buffered, and each
// wave runs up to 4 tile-computes between barriers (5 avg barriers/block).
// Longest groups first. Swapped QK^T 32x32x16, log2-domain scores, bare
// v_exp, cvt_pk pack, plane-major LDS layout (conflict-free b128).
__global__ __launch_bounds__(512, 4) void k_attn(
    const unsigned short* __restrict__ qws, const unsigned short* __restrict__ kv,
    float* __restrict__ out) {
  __shared__ __align__(16) unsigned short kvbuf[2][8192];   // quad buffers, 32KB
  int tid = threadIdx.x;
  int wid = tid >> 6, l = tid & 63;
  int col = l & 31, hi = l >> 5;
  int bh = (int)(blockIdx.x & 255);                   // XCD-pinned (256%8==0)
  int g  = 3 - (int)(blockIdx.x >> 8);                // longest groups first
  int qt = g * 8 + wid;                               // this wave's q-tile
  int q0 = qt << 5;
  int niter = g * 2 + 2;                              // quad-iterations

  const unsigned short* Q   = qws + (size_t)bh * S_ * HD;
  const unsigned short* kvb = kv + (size_t)bh * 32 * 2048;
  char* kb0 = (char*)&kvbuf[0][0];                    // buffer byte bases
  int wb = wid * 1024;                                // tid*16 = wid*1024+lane*16

  short8 aq0 = *reinterpret_cast<const short8*>(Q + (q0 + col) * HD + hi * 8);
  short8 aq1 = *reinterpret_cast<const short8*>(Q + (q0 + col) * HD + 16 + hi * 8);

  f32x16 z, O;
  #pragma unroll
  for (int i = 0; i < 16; ++i) { z[i] = 0.f; O[i] = 0.f; }
  float lsA = 0.f, lsB = 0.f;

  gl_lds16(kvb + tid * 8,        kb0 + wb);           // prologue: DMA quad 0
  gl_lds16(kvb + 4096 + tid * 8, kb0 + 8192 + wb);
  __syncthreads();

  #pragma unroll 1
  for (int i = 0; i < niter; ++i) {
    int cur = i & 1;
    bool more = (i + 1 < niter);
    if (more) {                                       // DMA next quad into cur^1
      const unsigned short* src = kvb + (size_t)(i + 1) * 8192 + tid * 8;
      char* dst = kb0 + (cur ^ 1) * 16384 + wb;
      gl_lds16(src,        dst);
      gl_lds16(src + 4096, dst + 8192);
    }

    #pragma unroll
    for (int sub = 0; sub < 4; ++sub) {
      int t = 4 * i + sub;
      if (qt >= t) {                                  // wave-uniform
        const unsigned short* Kb = &kvbuf[cur][sub * 2048];
        short8 bk0 = *reinterpret_cast<const short8*>(Kb + hi * 256 + col * 8);
        short8 bk1 = *reinterpret_cast<const short8*>(Kb + 512 + hi * 256 + col * 8);
        short8 av0 = *reinterpret_cast<const short8*>(Kb + 1024 + hi * 256 + col * 8);
        short8 av1 = *reinterpret_cast<const short8*>(Kb + 1536 + hi * 256 + col * 8);

        f32x16 st = __builtin_amdgcn_mfma_f32_32x32x16_bf16(bk0, aq0, z, 0, 0, 0);
        st = __builtin_amdgcn_mfma_f32_32x32x16_bf16(bk1, aq1, st, 0, 0, 0);

        float p[16];
        if (t == qt) {                                // diagonal: strict mask
          #pragma unroll
          for (int r = 0; r < 16; ++r) {
            int key = (r & 3) + 8 * (r >> 2) + 4 * hi;
            float e = __builtin_amdgcn_exp2f(st[r]);
            p[r] = (key < col) ? e : 0.f;
          }
        } else {
          #pragma unroll
          for (int r = 0; r < 16; ++r) p[r] = __builtin_amdgcn_exp2f(st[r]);
        }

        lsA += ((p[0] + p[1]) + (p[2] + p[3])) + ((p[4] + p[5]) + (p[6] + p[7]));
        lsB += ((p[8] + p[9]) + (p[10] + p[11])) + ((p[12] + p[13]) + (p[14] + p[15]));

        union { unsigned int u[8]; short8 v[2]; } pb;
        #pragma unroll
        for (int jj = 0; jj < 8; ++jj)
          asm("v_cvt_pk_bf16_f32 %0, %1, %2"
              : "=v"(pb.u[jj]) : "v"(p[2 * jj]), "v"(p[2 * jj + 1]));

        O = __builtin_amdgcn_mfma_f32_32x32x16_bf16(av0, pb.v[0], O, 0, 0, 0);
        O = __builtin_amdgcn_mfma_f32_32x32x16_bf16(av1, pb.v[1], O, 0, 0, 0);
      }
    }

    __syncthreads();                                  // drains vmcnt: DMA landed
  }

  float lsum = lsA + lsB;
  float ltot = lsum + __shfl_xor(lsum, 32);
  float linv = (ltot > 0.f) ? 1.f / ltot : 0.f;       // q==0 row -> all zeros
  int b = bh >> 3, h = bh & 7;
  float* ob = out + ((size_t)(b * 256 + h * 32)) * S_ + q0 + col;
  #pragma unroll
  for (int r = 0; r < 16; ++r) {
    int d = (r & 3) + 8 * (r >> 2) + 4 * hi;
    ob[(size_t)d * S_] = O[r] * linv;
  }
}

// ---------------------------------------------------------------------------
extern "C" void kernel_launch(void* const* d_in, const int* in_sizes, int n_in,
                              void* d_out, int out_size, void* d_ws, size_t ws_size,
                              hipStream_t stream) {
  const float* x   = (const float*)d_in[0];
  const float* qw  = (const float*)d_in[1];
  const float* qb  = (const float*)d_in[2];
  const float* kvw = (const float*)d_in[3];
  const float* kvb = (const float*)d_in[4];
  float* out = (float*)d_out;

  char* ws = (char*)d_ws;
  unsigned short* wt   = (unsigned short*)(ws + 0);         //   768*256*2 = 393216
  float*          bias = (float*)(ws + 393216);             //   768*4     = 3072
  unsigned short* xt   = (unsigned short*)(ws + 396288);    //  32*1024*256*2
  unsigned short* qws  = (unsigned short*)(ws + 17173504);  //  32*8*1024*32*2
  unsigned short* kv   = (unsigned short*)(ws + 33950720);  //  256*32*2048*2 = 33554432
                                                            //  ends at 67505152

  k_prep<<<8960, 256, 0, stream>>>(x, xt, qw, qb, kvw, kvb, wt, bias);
  k_proj<<<dim3(48, 32), 256, 0, stream>>>(wt, bias, xt, qws, kv);
  k_attn<<<1024, 512, 0, stream>>>(qws, kv, out);
}